// Round 1
// baseline (999.911 us; speedup 1.0000x reference)
//
#include <hip/hip_runtime.h>

// Problem constants (fixed by the reference)
#define SIZE 8192
#define FIN  8192          // inner dim of all three matvecs
#define NQ   (2*SIZE + 10) // 16394
#define NSIG (2*SIZE + 1)  // 16385

// ---------------------------------------------------------------------------
// y[r] = (relu?)(dot(W[r,:], x) + b[r]), W row-major [fout, FIN]
// One wave (64 lanes) per row, 4 rows per 256-thread block.
// float4 loads: lane l reads W[r, 4*(l + 64*m) .. +3]  -> fully coalesced,
// 1 KiB per wave per instruction. x is 32 KB, read coalesced -> L1 hits.
// ---------------------------------------------------------------------------
template <bool RELU>
__global__ __launch_bounds__(256) void matvec_kernel(
    const float* __restrict__ W, const float* __restrict__ x,
    const float* __restrict__ b, float* __restrict__ y, int fout)
{
    const int wave = threadIdx.x >> 6;
    const int lane = threadIdx.x & 63;
    const int row  = blockIdx.x * 4 + wave;
    if (row >= fout) return;

    const float4* __restrict__ Wr = (const float4*)(W + (size_t)row * FIN);
    const float4* __restrict__ xv = (const float4*)x;

    float4 acc = make_float4(0.f, 0.f, 0.f, 0.f);
#pragma unroll 8
    for (int k = lane; k < FIN / 4; k += 64) {
        float4 w4 = Wr[k];
        float4 x4 = xv[k];
        acc.x = fmaf(w4.x, x4.x, acc.x);
        acc.y = fmaf(w4.y, x4.y, acc.y);
        acc.z = fmaf(w4.z, x4.z, acc.z);
        acc.w = fmaf(w4.w, x4.w, acc.w);
    }
    float s = (acc.x + acc.y) + (acc.z + acc.w);
#pragma unroll
    for (int off = 32; off > 0; off >>= 1)
        s += __shfl_down(s, off, 64);

    if (lane == 0) {
        s += b[row];
        if (RELU) s = fmaxf(s, 0.0f);
        y[row] = s;
    }
}

// ---------------------------------------------------------------------------
// Sigma[k] = 0.1 * sum_{m=0..9} Q[k+m]   (valid conv with constant kernel)
// ---------------------------------------------------------------------------
__global__ __launch_bounds__(256) void sigma_kernel(
    const float* __restrict__ Q, float* __restrict__ Sigma)
{
    const int k = blockIdx.x * blockDim.x + threadIdx.x;
    if (k >= NSIG) return;
    float s = 0.f;
#pragma unroll
    for (int m = 0; m < 10; ++m) s += Q[k + m];
    Sigma[k] = 0.1f * s;
}

// ---------------------------------------------------------------------------
// Per sample i: 101-point linear interp of Sigma on the regular grid,
// Fermi window, trapezoid integrals I1, I2. out[i]=I1, out[SIZE+i]=-I2.
// Accumulation mirrors the reference: sum (y_j + y_{j+1}) * (E_{j+1}-E_j) / 2
// ---------------------------------------------------------------------------
__global__ __launch_bounds__(256) void interp_kernel(
    const float* __restrict__ x, const int* __restrict__ Wc_p,
    const float* __restrict__ Sigma, float* __restrict__ out)
{
    const int i = blockIdx.x * blockDim.x + threadIdx.x;
    if (i >= SIZE) return;

    const float Wc   = (float)(*Wc_p);
    const float xi   = x[i];
    const float step = Wc / (float)SIZE;   // grid spacing of linspace(-Wc,Wc,2*SIZE+1)

    float I1 = 0.f, I2 = 0.f;
    float py1 = 0.f, py2 = 0.f, pE = 0.f;

    for (int j = 0; j <= 100; ++j) {
        // t_j = linspace(-1,1,101)[j] * Wc
        float t = fmaf((float)j, 0.02f, -1.0f) * Wc;
        float E = xi * t;
        // linear interpolation of Sigma
        float pos = (E + Wc) / step;
        int i0 = (int)floorf(pos);
        i0 = min(max(i0, 0), 2 * SIZE - 1);
        float frac = pos - (float)i0;
        float Sint = Sigma[i0] * (1.0f - frac) + Sigma[i0 + 1] * frac;
        // Fermi window / T
        float u  = E / xi;
        float eu = expf(u);
        float d  = eu + 1.0f;
        float w  = eu / (d * d) / xi;
        float y1 = Sint * w;
        float y2 = E * y1;
        if (j > 0) {
            float dE = E - pE;
            I1 += (y1 + py1) * dE;
            I2 += (y2 + py2) * dE;
        }
        py1 = y1; py2 = y2; pE = E;
    }
    out[i]        =  0.5f * I1;
    out[SIZE + i] = -0.5f * I2;
}

// ---------------------------------------------------------------------------
extern "C" void kernel_launch(void* const* d_in, const int* in_sizes, int n_in,
                              void* d_out, int out_size, void* d_ws, size_t ws_size,
                              hipStream_t stream)
{
    const float* x  = (const float*)d_in[0];
    const int*   Wc = (const int*)d_in[1];
    const float* W1 = (const float*)d_in[2];
    const float* b1 = (const float*)d_in[3];
    const float* W2 = (const float*)d_in[4];
    const float* b2 = (const float*)d_in[5];
    const float* W3 = (const float*)d_in[6];
    const float* b3 = (const float*)d_in[7];
    float* out = (float*)d_out;

    // workspace layout (floats)
    float* h1    = (float*)d_ws;               // SIZE
    float* h2    = h1 + SIZE;                  // SIZE
    float* Q     = h2 + SIZE;                  // NQ
    float* Sigma = Q + NQ;                     // NSIG

    dim3 blk(256);
    // 4 rows (waves) per block
    matvec_kernel<true ><<<dim3(SIZE / 4),       blk, 0, stream>>>(W1, x,  b1, h1, SIZE);
    matvec_kernel<true ><<<dim3(SIZE / 4),       blk, 0, stream>>>(W2, h1, b2, h2, SIZE);
    matvec_kernel<false><<<dim3((NQ + 3) / 4),   blk, 0, stream>>>(W3, h2, b3, Q,  NQ);
    sigma_kernel <<<dim3((NSIG + 255) / 256),    blk, 0, stream>>>(Q, Sigma);
    interp_kernel<<<dim3(SIZE / 256),            blk, 0, stream>>>(x, Wc, Sigma, out);
}